// Round 13
// baseline (371.366 us; speedup 1.0000x reference)
//
#include <hip/hip_runtime.h>
#include <hip/hip_bf16.h>

#define NPOS 6912
#define HW   2304
#define C    256
#define EPSG 1e-6f
// softmax scale folded with log2(e): exp(s*0.0625) = exp2(s*K2)
#define K2 (0.0625f * 1.4426950408889634f)

typedef __attribute__((ext_vector_type(8))) short bf16x8;  // 8 bf16 in 4 VGPRs
typedef __attribute__((ext_vector_type(4))) float f32x4;
typedef __attribute__((ext_vector_type(16))) float f32x16;
typedef __attribute__((ext_vector_type(8))) int v8i;       // 32B fp8 operand
typedef long long i64;
typedef unsigned char u8;

__device__ __forceinline__ unsigned short f2bf(float f) {
    union { float f; unsigned int u; } v; v.f = f;
    unsigned int lsb = (v.u >> 16) & 1u;
    return (unsigned short)((v.u + 0x7fffu + lsb) >> 16);
}

// f32 -> fp8 e4m3fn (OCP), RNE, with subnormal handling.
__device__ __forceinline__ u8 f2fp8(float f) {
    union { float f; unsigned u; } v; v.f = f;
    unsigned sgn = (v.u >> 24) & 0x80u;
    unsigned a = v.u & 0x7FFFFFFFu;
    if (a >= 0x3C800000u) {                       // |f| >= 2^-6 : normal
        unsigned r = a + 0x000FFFFFu + ((a >> 20) & 1u);
        return (u8)(sgn | ((r >> 20) - 0x3C0u));
    }
    union { unsigned u; float f; } w2; w2.u = a;
    int mnt = (int)rintf(w2.f * 512.0f);          // subnormal: step 2^-9
    return (u8)(sgn | (unsigned)mnt);
}

// fp8 e4m3fn -> f32, branchless
__device__ __forceinline__ float fp8tof(u8 v) {
    unsigned u = ((unsigned)(v & 0x80u) << 24) | ((((unsigned)(v & 0x7Fu)) + 960u) << 20);
    union { unsigned u; float f; } w; w.u = u;
    return w.f;
}

#define MFMA(a, b, c)  __builtin_amdgcn_mfma_f32_16x16x32_bf16((a), (b), (c), 0, 0, 0)
// MX-scaled fp8 (fmt 0 = e4m3), unit scale e8m0=127 replicated in all bytes so any
// opsel byte-select still yields 2^0.
#define MFMAS16(a, b, c) __builtin_amdgcn_mfma_scale_f32_16x16x128_f8f6f4((a), (b), (c), 0, 0, 0, 0x7F7F7F7F, 0, 0x7F7F7F7F)
#define MFMAS32(a, b, c) __builtin_amdgcn_mfma_scale_f32_32x32x64_f8f6f4((a), (b), (c), 0, 0, 0, 0x7F7F7F7F, 0, 0x7F7F7F7F)

__device__ __forceinline__ v8i mk8(int4 lo, int4 hi) {
    v8i r;
    r[0] = lo.x; r[1] = lo.y; r[2] = lo.z; r[3] = lo.w;
    r[4] = hi.x; r[5] = hi.y; r[6] = hi.z; r[7] = hi.w;
    return r;
}

// async global->LDS, 16B per lane; dest wave-uniform base (lane*16 implicit)
__device__ __forceinline__ void gld16(const u8* g, const char* l) {
    __builtin_amdgcn_global_load_lds(
        (const __attribute__((address_space(1))) void*)(unsigned long long)g,
        (__attribute__((address_space(3))) void*)(unsigned int)(unsigned long long)l,
        16, 0, 0);
}

// ===== fp8 frag-major layouts for scaled MFMA (32B/lane, half-split: lane stride 16B) ===
// Q/K (A/B of 16x16x128): frag 2048B = ((b*108 + n>>6)*4 + (n>>4)&3)*2 + (c>>7);
//   within: ((c>>4)&1)*1024 + (((c>>5)&3)*16 + (n&15))*16 + (c&15)
// V (B of 32x32x64): frag 2048B = (b*108 + n>>6)*8 + (c>>5);
//   within: ((n>>4)&1)*1024 + (((n>>5)&1)*32 + (c&31))*16 + (n&15)

// ---------------- GroupNorm stats (864 blocks x 16 iters) + weights->frag-major bf16 ------
__global__ __launch_bounds__(256) void gn_stats(const float* x, float* part,
                                                const float* wq, const float* wk,
                                                const float* wv, const float* wp,
                                                unsigned short* wbf) {
    if (blockIdx.x < 256) {                       // fused weight conversion (bf16 8B-granule)
        int i = blockIdx.x * 256 + threadIdx.x;
        int o = i >> 8, c = i & 255;
        int pos = (((o >> 6) * 4 + ((o >> 4) & 3)) * 8 + (c >> 5)) * 512
                + (((c >> 3) & 3) * 16 + (o & 15)) * 8 + (c & 7);
        wbf[pos]          = f2bf(wq[i]);
        wbf[65536 + pos]  = f2bf(wk[i]);
        wbf[131072 + pos] = f2bf(wv[i]);
        wbf[196608 + pos] = f2bf(wp[i]);
    }
    int gid = blockIdx.x / 108, slice = blockIdx.x % 108;  // 8 groups x 108 slices
    int b = gid >> 2, grp = gid & 3;
    float s = 0.f, s2 = 0.f;
    #pragma unroll
    for (int k = 0; k < 16; ++k) {
        int e = slice * 4096 + k * 256 + (int)threadIdx.x;   // 0..442367 per group
        int f = e / 147456; int r1 = e - f * 147456;
        int ch = r1 / HW;   int sp = r1 - ch * HW;
        float v = x[(size_t)((f * 2 + b) * C + grp * 64 + ch) * HW + sp];
        s += v; s2 += v * v;
    }
    #pragma unroll
    for (int off = 32; off; off >>= 1) { s += __shfl_xor(s, off); s2 += __shfl_xor(s2, off); }
    __shared__ float ls[8];
    int w = threadIdx.x >> 6;
    if ((threadIdx.x & 63) == 0) { ls[w * 2] = s; ls[w * 2 + 1] = s2; }
    __syncthreads();
    if (threadIdx.x == 0) {
        float t = 0.f, t2 = 0.f;
        for (int i2 = 0; i2 < 4; ++i2) { t += ls[i2 * 2]; t2 += ls[i2 * 2 + 1]; }
        part[blockIdx.x * 2] = t; part[blockIdx.x * 2 + 1] = t2;
    }
}

// ---------------- GN apply (stats finalize folded in) -> hn FRAG-MAJOR bf16 ----------------
__global__ __launch_bounds__(256) void gn_apply(const float* x, const float* part,
                                                const float* gsc, const float* gbi,
                                                unsigned short* hnf) {
    int blk = blockIdx.x;                 // 2*3*48 = 288
    int b = blk / 144; int f = (blk % 144) / 48; int y = blk % 48;
    int c = threadIdx.x;
    int gid = b * 4 + (c >> 6);
    float s = 0.f, s2 = 0.f;              // finalize stats from 108 slice partials
    for (int i = 0; i < 108; ++i) {
        s  += part[(gid * 108 + i) * 2];
        s2 += part[(gid * 108 + i) * 2 + 1];
    }
    float mean = s / 442368.f;
    float rsig = rsqrtf(s2 / 442368.f - mean * mean + EPSG);
    float sc = gsc[c] * rsig, bi = gbi[c] - mean * sc;
    __shared__ unsigned short lds[48 * 256];
    const float* xr = x + (size_t)((f * 2 + b) * C + c) * HW + y * 48;
    #pragma unroll
    for (int xw = 0; xw < 48; xw += 4) {
        float4 v = *(const float4*)(xr + xw);
        lds[(xw + 0) * 256 + c] = f2bf(v.x * sc + bi);
        lds[(xw + 1) * 256 + c] = f2bf(v.y * sc + bi);
        lds[(xw + 2) * 256 + c] = f2bf(v.z * sc + bi);
        lds[(xw + 3) * 256 + c] = f2bf(v.w * sc + bi);
    }
    __syncthreads();
    int kc = c >> 5, gg = (c >> 3) & 3, j = c & 7;
    int nbase = f * HW + y * 48;
    for (int xw = 0; xw < 48; ++xw) {
        int n = nbase + xw;
        size_t idx = ((size_t)(((b * 108 + (n >> 6)) * 4 + ((n >> 4) & 3)) * 8 + kc)) * 512
                   + (gg * 16 + (n & 15)) * 8 + j;
        hnf[idx] = lds[xw * 256 + c];
    }
}

// ---------------- fused Q/K/V GEMM -> scaled-MFMA fp8 frag layouts ----------------
__global__ __launch_bounds__(256) void qkv_gemm(const unsigned short* hnf, const unsigned short* wbf,
                                                const float* bq, const float* bk, const float* bvp,
                                                u8* qfp, u8* kfp, u8* vfp) {
    __shared__ u8 tr[4096];
    int t = blockIdx.x;
    int tid = (int)threadIdx.x;
    int lane = tid & 63, w = tid >> 6;
    int l16 = lane & 15, g = lane >> 4;
    f32x4 acc[4] = {{0.f,0.f,0.f,0.f},{0.f,0.f,0.f,0.f},{0.f,0.f,0.f,0.f},{0.f,0.f,0.f,0.f}};
    if (t < 1728) {
        int sel = t / 864; int rem = t % 864;
        int b = rem / 432;  int rem2 = rem % 432;
        int pt = rem2 >> 2; int ot = rem2 & 3;
        const unsigned short* wsel = wbf + sel * 65536;
        const float* bias = sel ? bk : bq;
        u8* out = sel ? kfp : qfp;
        const unsigned short* af  = hnf + (size_t)(((b * 108 + pt) * 4 + w) * 8) * 512 + lane * 8;
        const unsigned short* bfm = wsel + (size_t)(ot * 4 * 8) * 512 + lane * 8;
        #pragma unroll
        for (int kk = 0; kk < 8; ++kk) {
            bf16x8 a = *(const bf16x8*)(af + kk * 512);
            #pragma unroll
            for (int f = 0; f < 4; ++f) {
                bf16x8 bb = *(const bf16x8*)(bfm + (f * 8 + kk) * 512);
                acc[f] = MFMA(a, bb, acc[f]);
            }
        }
        // scatter to LDS (n = pt*64 + w*16 + 4g+r, c = ot*64 + f*16 + l16)
        #pragma unroll
        for (int f = 0; f < 4; ++f) {
            float bv = bias[ot * 64 + f * 16 + l16];
            #pragma unroll
            for (int r = 0; r < 4; ++r)
                tr[w * 1024 + (f & 1) * 512 + ((f >> 1) * 16 + 4 * g + r) * 16 + l16]
                    = f2fp8(acc[f][r] + bv);
        }
        __syncthreads();
        int t2 = tid >> 6, hf = (tid >> 5) & 1, ln = tid & 31;
        size_t frag = ((size_t)(b * 108 + pt) * 4 + t2) * 2 + (ot >> 1);
        *(int4*)(out + frag * 2048 + hf * 1024 + ((ot & 1) * 32 + ln) * 16)
            = *(const int4*)(tr + tid * 16);
    } else {
        int tv = t - 1728;                        // 864 = 2 b * 4 ot * 108 pt
        int b = tv / 432; int rem2 = tv % 432;
        int ot = rem2 / 108; int pt = rem2 % 108;
        const unsigned short* wvw = wbf + 131072;
        const unsigned short* afm = wvw + (size_t)((ot * 4 + w) * 8) * 512 + lane * 8;
        const unsigned short* bfm = hnf + (size_t)((b * 108 + pt) * 4 * 8) * 512 + lane * 8;
        #pragma unroll
        for (int kk = 0; kk < 8; ++kk) {
            bf16x8 a = *(const bf16x8*)(afm + kk * 512);
            #pragma unroll
            for (int f = 0; f < 4; ++f) {
                bf16x8 bb = *(const bf16x8*)(bfm + (f * 8 + kk) * 512);
                acc[f] = MFMA(a, bb, acc[f]);
            }
        }
        // V (c-row = ot*64 + w*16 + 4g+r, n = pt*64 + f*16 + l16)
        #pragma unroll
        for (int f = 0; f < 4; ++f) {
            #pragma unroll
            for (int r = 0; r < 4; ++r) {
                int o = ot * 64 + w * 16 + 4 * g + r;
                tr[(w >> 1) * 2048 + (f & 1) * 1024
                   + ((f >> 1) * 32 + (w & 1) * 16 + 4 * g + r) * 16 + l16]
                    = f2fp8(acc[f][r] + bvp[o]);
            }
        }
        __syncthreads();
        size_t frag = (size_t)(b * 108 + pt) * 8 + ot * 2 + (tid >> 7);
        *(int4*)(vfp + frag * 2048 + (tid & 127) * 16) = *(const int4*)(tr + tid * 16);
    }
}

// ---------------- flash attention: MX-scaled fp8, triple-buffered software pipeline -------
// 216 blocks x 512 threads, 8 waves x 32 q-rows. Pipeline: body(t) = { barrier;
// stage(t+2)->buf[(t+2)%3]; QK(t+1)->S_next (regs, data staged a full iter earlier);
// softmax(S_cur)->P; PV(t) }. QK never waits on fresh vmem; barrier's implicit vmcnt(0)
// drains loads issued one body earlier (latency hidden); QK-MFMA co-issues with
// softmax-VALU (independent). Two named score sets sA/sB (rule #20), 2-unrolled loop.
__global__ __launch_bounds__(512, 2) void flash(const u8* qf, const u8* kf, const u8* vf,
                                                u8* po, float* lsg) {
    __shared__ char smem[114688];                 // 3 x 32KB K/V triple-buffer + 8 x 2KB P
    int blk = blockIdx.x;                         // 216 = 8 XCD slots x 27 q-tiles(256)
    int x = blk & 7, qt = blk >> 3;
    int b = x >> 2, ks = x & 3;                   // XCD-pinned (b, KV-quarter)
    int slot = ks * 2 + b;
    int tid = (int)threadIdx.x;
    int lane = tid & 63, w = tid >> 6;            // w = wave 0..7
    int l16 = lane & 15, g = lane >> 4;
    int i0 = qt * 256 + w * 32;                   // wave covers 32 q-rows

    // Q B-frags (16x16x128): per (group u, c-half h) 32B/lane
    v8i qa[2][2];
    #pragma unroll
    for (int u = 0; u < 2; ++u)
        #pragma unroll
        for (int h = 0; h < 2; ++h) {
            const u8* qb = qf + ((((size_t)b * 108 + qt * 4 + (w >> 1)) * 4
                                  + ((2 * w + u) & 3)) * 2 + h) * 2048 + lane * 16;
            qa[u][h] = mk8(*(const int4*)qb, *(const int4*)(qb + 1024));
        }

    // staging: flat linear copy of 16KB frag-major tiles (advance 16KB/iter)
    size_t tb = (size_t)(b * 108 + ks * 27) * 16384;
    const u8* kst[2]; const u8* vst[2];
    #pragma unroll
    for (int q = 0; q < 2; ++q) {
        kst[q] = kf + tb + (q * 8 + w) * 1024 + lane * 16;
        vst[q] = vf + tb + (q * 8 + w) * 1024 + lane * 16;
    }
    // prologue: stage tiles 0 and 1 into bufs 0,1
    #pragma unroll
    for (int q = 0; q < 2; ++q) {
        gld16(kst[q], smem + (q * 8 + w) * 1024);
        gld16(vst[q], smem + 16384 + (q * 8 + w) * 1024);
        kst[q] += 16384; vst[q] += 16384;
    }
    #pragma unroll
    for (int q = 0; q < 2; ++q) {
        gld16(kst[q], smem + 32768 + (q * 8 + w) * 1024);
        gld16(vst[q], smem + 32768 + 16384 + (q * 8 + w) * 1024);
        kst[q] += 16384; vst[q] += 16384;
    }

    f32x16 oacc[8];
    #pragma unroll
    for (int ct = 0; ct < 8; ++ct)
        #pragma unroll
        for (int r = 0; r < 16; ++r) oacc[ct][r] = 0.f;
    float lsum0 = 0.f, lsum1 = 0.f;
    int pbase = 98304 + w * 2048;                 // per-wave P region
    f32x4 sA[2][4], sB[2][4];
    int bc = 0, bn = 32768, bs = 65536;           // buffer byte offsets, rotate per body

    __syncthreads();                              // tiles 0,1 resident

    // QK(0) from buf 0 -> sA
    {
        #pragma unroll
        for (int u = 0; u < 2; ++u)
            #pragma unroll
            for (int tt = 0; tt < 4; ++tt) sA[u][tt] = (f32x4){0.f,0.f,0.f,0.f};
        __builtin_amdgcn_s_setprio(1);
        #pragma unroll
        for (int tt = 0; tt < 4; ++tt)
            #pragma unroll
            for (int h = 0; h < 2; ++h) {
                const char* ka = smem + (tt * 2 + h) * 2048 + lane * 16;
                v8i a = mk8(*(const int4*)ka, *(const int4*)(ka + 1024));
                sA[0][tt] = MFMAS16(a, qa[0][h], sA[0][tt]);
                sA[1][tt] = MFMAS16(a, qa[1][h], sA[1][tt]);
            }
        __builtin_amdgcn_s_setprio(0);
    }

#define FBODY(T, SCUR, SNXT) {                                                    \
    __syncthreads();                                                              \
    if ((T) + 2 < 27) {                                                           \
        _Pragma("unroll")                                                         \
        for (int q = 0; q < 2; ++q) {                                             \
            gld16(kst[q], smem + bs + (q * 8 + w) * 1024);                        \
            gld16(vst[q], smem + bs + 16384 + (q * 8 + w) * 1024);                \
            kst[q] += 16384; vst[q] += 16384;                                     \
        }                                                                         \
    }                                                                             \
    if ((T) + 1 < 27) {                                                           \
        _Pragma("unroll")                                                         \
        for (int u = 0; u < 2; ++u) {                                             \
            _Pragma("unroll")                                                     \
            for (int tt = 0; tt < 4; ++tt) SNXT[u][tt] = (f32x4){0.f,0.f,0.f,0.f};\
        }                                                                         \
        __builtin_amdgcn_s_setprio(1);                                            \
        _Pragma("unroll")                                                         \
        for (int tt = 0; tt < 4; ++tt) {                                          \
            _Pragma("unroll")                                                     \
            for (int h = 0; h < 2; ++h) {                                         \
                const char* ka = smem + bn + (tt * 2 + h) * 2048 + lane * 16;     \
                v8i a = mk8(*(const int4*)ka, *(const int4*)(ka + 1024));         \
                SNXT[0][tt] = MFMAS16(a, qa[0][h], SNXT[0][tt]);                  \
                SNXT[1][tt] = MFMAS16(a, qa[1][h], SNXT[1][tt]);                  \
            }                                                                     \
        }                                                                         \
        __builtin_amdgcn_s_setprio(0);                                            \
    }                                                                             \
    _Pragma("unroll")                                                             \
    for (int u = 0; u < 2; ++u) {                                                 \
        float rs = 0.f;                                                           \
        _Pragma("unroll")                                                         \
        for (int tt = 0; tt < 4; ++tt) {                                          \
            float p0 = __builtin_amdgcn_exp2f(fminf(SCUR[u][tt][0] * K2, 8.f));   \
            float p1 = __builtin_amdgcn_exp2f(fminf(SCUR[u][tt][1] * K2, 8.f));   \
            float p2 = __builtin_amdgcn_exp2f(fminf(SCUR[u][tt][2] * K2, 8.f));   \
            float p3 = __builtin_amdgcn_exp2f(fminf(SCUR[u][tt][3] * K2, 8.f));   \
            rs += (p0 + p1) + (p2 + p3);                                          \
            int lo = __builtin_amdgcn_cvt_pk_fp8_f32(p0, p1, 0, false);           \
            int d  = __builtin_amdgcn_cvt_pk_fp8_f32(p2, p3, lo, true);           \
            *(int*)(smem + pbase + u * 1024 + (tt >> 1) * 512 + l16 * 32          \
                    + (tt & 1) * 16 + g * 4) = d;                                 \
        }                                                                         \
        rs += __shfl_xor(rs, 16);                                                 \
        rs += __shfl_xor(rs, 32);                                                 \
        if (u == 0) lsum0 += rs; else lsum1 += rs;                                \
    }                                                                             \
    {                                                                             \
        const char* pp = smem + pbase + ((lane >> 4) & 1) * 1024                  \
                       + (lane >> 5) * 512 + l16 * 32;                            \
        v8i pa = mk8(*(const int4*)pp, *(const int4*)(pp + 16));                  \
        __builtin_amdgcn_s_setprio(1);                                            \
        _Pragma("unroll")                                                         \
        for (int ct = 0; ct < 8; ++ct) {                                          \
            const char* va = smem + bc + 16384 + ct * 2048 + lane * 16;           \
            v8i vv = mk8(*(const int4*)va, *(const int4*)(va + 1024));            \
            oacc[ct] = MFMAS32(pa, vv, oacc[ct]);                                 \
        }                                                                         \
        __builtin_amdgcn_s_setprio(0);                                            \
    }                                                                             \
    { int _t = bc; bc = bn; bn = bs; bs = _t; }                                   \
}

    for (int t = 0; t < 26; t += 2) {
        FBODY(t, sA, sB);
        FBODY(t + 1, sB, sA);
    }
    FBODY(26, sA, sB);
#undef FBODY

    // epilogue: unnormalized partials (fp8, 32x32 D layout) + lsum (f32)
    #pragma unroll
    for (int ct = 0; ct < 8; ++ct)
        #pragma unroll
        for (int r = 0; r < 16; ++r) {
            int n = i0 + (r & 3) + 8 * (r >> 2) + 4 * (lane >> 5);
            po[((size_t)slot * NPOS + n) * C + ct * 32 + (lane & 31)] = f2fp8(oacc[ct][r]);
        }
    if (lane < 16) {
        lsg[(size_t)slot * NPOS + i0 + lane]      = lsum0;
        lsg[(size_t)slot * NPOS + i0 + 16 + lane] = lsum1;
    }
}

// ---------------- proj (+ inline 4-way split combine) + bias + residual ----------------
__global__ __launch_bounds__(256) void proj(const u8* po, const float* lsg,
                                            const unsigned short* wbf,
                                            const float* bp, const float* x, float* out) {
    int t = blockIdx.x;                  // 2 b * 108 pt * 4 ot = 864
    int b = t / 432; int rem2 = t % 432;
    int pt = rem2 >> 2; int ot = rem2 & 3;
    int lane = threadIdx.x & 63, w = threadIdx.x >> 6;
    int l16 = lane & 15, g = lane >> 4;
    int n = pt * 64 + w * 16 + l16;      // this lane's A row
    float l = 0.f;
    #pragma unroll
    for (int ks2 = 0; ks2 < 4; ++ks2) l += lsg[(size_t)(ks2 * 2 + b) * NPOS + n];
    float rl = 1.f / l;
    const unsigned short* wpw = wbf + 196608;
    const unsigned short* bfm = wpw + (size_t)(ot * 4 * 8) * 512 + lane * 8;
    const u8* prow = po + ((size_t)b * NPOS + n) * C + g * 8;   // + ks2*2*NPOS*C + kk*32
    f32x4 acc[4] = {{0.f,0.f,0.f,0.f},{0.f,0.f,0.f,0.f},{0.f,0.f,0.f,0.f},{0.f,0.f,0.f,0.f}};
    #pragma unroll
    for (int kk = 0; kk < 8; ++kk) {
        float av0 = 0.f, av1 = 0.f, av2 = 0.f, av3 = 0.f;
        float av4 = 0.f, av5 = 0.f, av6 = 0.f, av7 = 0.f;
        #pragma unroll
        for (int ks2 = 0; ks2 < 4; ++ks2) {
            i64 p8 = *(const i64*)(prow + (size_t)ks2 * (2 * NPOS * 256) + kk * 32);
            av0 += fp8tof((u8)(p8));        av1 += fp8tof((u8)(p8 >> 8));
            av2 += fp8tof((u8)(p8 >> 16));  av3 += fp8tof((u8)(p8 >> 24));
            av4 += fp8tof((u8)(p8 >> 32));  av5 += fp8tof((u8)(p8 >> 40));
            av6 += fp8tof((u8)(p8 >> 48));  av7 += fp8tof((u8)(p8 >> 56));
        }
        bf16x8 a;
        a[0] = (short)f2bf(av0 * rl); a[1] = (short)f2bf(av1 * rl);
        a[2] = (short)f2bf(av2 * rl); a[3] = (short)f2bf(av3 * rl);
        a[4] = (short)f2bf(av4 * rl); a[5] = (short)f2bf(av5 * rl);
        a[6] = (short)f2bf(av6 * rl); a[7] = (short)f2bf(av7 * rl);
        #pragma unroll
        for (int f = 0; f < 4; ++f) {
            bf16x8 bb = *(const bf16x8*)(bfm + (f * 8 + kk) * 512);
            acc[f] = MFMA(a, bb, acc[f]);
        }
    }
    __shared__ float lt[64][72];
    #pragma unroll
    for (int f = 0; f < 4; ++f) {
        float bv = bp[ot * 64 + f * 16 + l16];
        #pragma unroll
        for (int r = 0; r < 4; ++r)
            lt[f * 16 + l16][w * 16 + 4 * g + r] = acc[f][r] + bv;
    }
    __syncthreads();
    int p0 = pt * 64;
    int f3 = p0 / HW; int sp0 = p0 - f3 * HW;     // 64 | 2304 so whole tile same f
    for (int it = 0; it < 16; ++it) {
        int ol = it * 4 + w;
        int pl = lane;
        size_t idx = ((size_t)(b * 3 + f3) * C + ot * 64 + ol) * HW + sp0 + pl;
        out[idx] = x[idx] + lt[ol][pl];
    }
}

extern "C" void kernel_launch(void* const* d_in, const int* in_sizes, int n_in,
                              void* d_out, int out_size, void* d_ws, size_t ws_size,
                              hipStream_t stream) {
    const float* x   = (const float*)d_in[0];
    const float* gsc = (const float*)d_in[1];
    const float* gbi = (const float*)d_in[2];
    const float* wq  = (const float*)d_in[3];
    const float* bq  = (const float*)d_in[4];
    const float* wk  = (const float*)d_in[5];
    const float* bk  = (const float*)d_in[6];
    const float* wv  = (const float*)d_in[7];
    const float* bv  = (const float*)d_in[8];
    const float* wp  = (const float*)d_in[9];
    const float* bp  = (const float*)d_in[10];

    char* ws = (char*)d_ws;
    unsigned short* wbf = (unsigned short*)(ws);             // 524288 B
    float* part         = (float*)(ws + 524288);             // 6912 B (8 groups x 108 x 2)
    unsigned short* hn  = (unsigned short*)(ws + 532480);    // 7077888 B (frag-major)
    u8* qfp             = (u8*)(ws + 7610368);               // 3538944 B
    u8* kfp             = (u8*)(ws + 11149312);              // 3538944 B
    u8* vfp             = (u8*)(ws + 14688256);              // 3538944 B
    u8* po              = (u8*)(ws + 18227200);              // 14155776 B (4ks x 2b x n x c)
    float* lsg          = (float*)(ws + 32382976);           // 221184 B -> end 32604160
    float* out = (float*)d_out;

    hipLaunchKernelGGL(gn_stats, dim3(864),  dim3(256), 0, stream, x, part, wq, wk, wv, wp, wbf);
    hipLaunchKernelGGL(gn_apply, dim3(288),  dim3(256), 0, stream, x, part, gsc, gbi, hn);
    hipLaunchKernelGGL(qkv_gemm, dim3(2592), dim3(256), 0, stream, hn, wbf, bq, bk, bv, qfp, kfp, vfp);
    hipLaunchKernelGGL(flash,    dim3(216),  dim3(512), 0, stream, qfp, kfp, vfp, po, lsg);
    hipLaunchKernelGGL(proj,     dim3(864),  dim3(256), 0, stream, po, lsg, wbf, bp, x, out);
}

// Round 14
// 135.602 us; speedup vs baseline: 2.7387x; 2.7387x over previous
//
#include <hip/hip_runtime.h>
#include <hip/hip_bf16.h>

#define NPOS 6912
#define HW   2304
#define C    256
#define EPSG 1e-6f
// softmax scale folded with log2(e): exp(s*0.0625) = exp2(s*K2)
#define K2 (0.0625f * 1.4426950408889634f)

typedef __attribute__((ext_vector_type(8))) short bf16x8;  // 8 bf16 in 4 VGPRs
typedef __attribute__((ext_vector_type(4))) float f32x4;
typedef __attribute__((ext_vector_type(16))) float f32x16;
typedef __attribute__((ext_vector_type(8))) int v8i;       // 32B fp8 operand
typedef long long i64;
typedef unsigned char u8;

__device__ __forceinline__ unsigned short f2bf(float f) {
    union { float f; unsigned int u; } v; v.f = f;
    unsigned int lsb = (v.u >> 16) & 1u;
    return (unsigned short)((v.u + 0x7fffu + lsb) >> 16);
}

// f32 -> fp8 e4m3fn (OCP), RNE, with subnormal handling.
__device__ __forceinline__ u8 f2fp8(float f) {
    union { float f; unsigned u; } v; v.f = f;
    unsigned sgn = (v.u >> 24) & 0x80u;
    unsigned a = v.u & 0x7FFFFFFFu;
    if (a >= 0x3C800000u) {                       // |f| >= 2^-6 : normal
        unsigned r = a + 0x000FFFFFu + ((a >> 20) & 1u);
        return (u8)(sgn | ((r >> 20) - 0x3C0u));
    }
    union { unsigned u; float f; } w2; w2.u = a;
    int mnt = (int)rintf(w2.f * 512.0f);          // subnormal: step 2^-9
    return (u8)(sgn | (unsigned)mnt);
}

// fp8 e4m3fn -> f32, branchless
__device__ __forceinline__ float fp8tof(u8 v) {
    unsigned u = ((unsigned)(v & 0x80u) << 24) | ((((unsigned)(v & 0x7Fu)) + 960u) << 20);
    union { unsigned u; float f; } w; w.u = u;
    return w.f;
}

#define MFMA(a, b, c)  __builtin_amdgcn_mfma_f32_16x16x32_bf16((a), (b), (c), 0, 0, 0)
// MX-scaled fp8 (fmt 0 = e4m3), unit scale e8m0=127 replicated in all bytes so any
// opsel byte-select still yields 2^0.
#define MFMAS16(a, b, c) __builtin_amdgcn_mfma_scale_f32_16x16x128_f8f6f4((a), (b), (c), 0, 0, 0, 0x7F7F7F7F, 0, 0x7F7F7F7F)
#define MFMAS32(a, b, c) __builtin_amdgcn_mfma_scale_f32_32x32x64_f8f6f4((a), (b), (c), 0, 0, 0, 0x7F7F7F7F, 0, 0x7F7F7F7F)

__device__ __forceinline__ v8i mk8(int4 lo, int4 hi) {
    v8i r;
    r[0] = lo.x; r[1] = lo.y; r[2] = lo.z; r[3] = lo.w;
    r[4] = hi.x; r[5] = hi.y; r[6] = hi.z; r[7] = hi.w;
    return r;
}

// async global->LDS, 16B per lane; dest wave-uniform base (lane*16 implicit)
__device__ __forceinline__ void gld16(const u8* g, const char* l) {
    __builtin_amdgcn_global_load_lds(
        (const __attribute__((address_space(1))) void*)(unsigned long long)g,
        (__attribute__((address_space(3))) void*)(unsigned int)(unsigned long long)l,
        16, 0, 0);
}

// ===== fp8 frag-major layouts for scaled MFMA (32B/lane, half-split: lane stride 16B) ===
// Q/K (A/B of 16x16x128): frag 2048B = ((b*108 + n>>6)*4 + (n>>4)&3)*2 + (c>>7);
//   within: ((c>>4)&1)*1024 + (((c>>5)&3)*16 + (n&15))*16 + (c&15)
// V (B of 32x32x64): frag 2048B = (b*108 + n>>6)*8 + (c>>5);
//   within: ((n>>4)&1)*1024 + (((n>>5)&1)*32 + (c&31))*16 + (n&15)

// ---------------- GroupNorm stats (864 blocks x 16 iters) + weights->frag-major bf16 ------
__global__ __launch_bounds__(256) void gn_stats(const float* x, float* part,
                                                const float* wq, const float* wk,
                                                const float* wv, const float* wp,
                                                unsigned short* wbf) {
    if (blockIdx.x < 256) {                       // fused weight conversion (bf16 8B-granule)
        int i = blockIdx.x * 256 + threadIdx.x;
        int o = i >> 8, c = i & 255;
        int pos = (((o >> 6) * 4 + ((o >> 4) & 3)) * 8 + (c >> 5)) * 512
                + (((c >> 3) & 3) * 16 + (o & 15)) * 8 + (c & 7);
        wbf[pos]          = f2bf(wq[i]);
        wbf[65536 + pos]  = f2bf(wk[i]);
        wbf[131072 + pos] = f2bf(wv[i]);
        wbf[196608 + pos] = f2bf(wp[i]);
    }
    int gid = blockIdx.x / 108, slice = blockIdx.x % 108;  // 8 groups x 108 slices
    int b = gid >> 2, grp = gid & 3;
    float s = 0.f, s2 = 0.f;
    #pragma unroll
    for (int k = 0; k < 16; ++k) {
        int e = slice * 4096 + k * 256 + (int)threadIdx.x;   // 0..442367 per group
        int f = e / 147456; int r1 = e - f * 147456;
        int ch = r1 / HW;   int sp = r1 - ch * HW;
        float v = x[(size_t)((f * 2 + b) * C + grp * 64 + ch) * HW + sp];
        s += v; s2 += v * v;
    }
    #pragma unroll
    for (int off = 32; off; off >>= 1) { s += __shfl_xor(s, off); s2 += __shfl_xor(s2, off); }
    __shared__ float ls[8];
    int w = threadIdx.x >> 6;
    if ((threadIdx.x & 63) == 0) { ls[w * 2] = s; ls[w * 2 + 1] = s2; }
    __syncthreads();
    if (threadIdx.x == 0) {
        float t = 0.f, t2 = 0.f;
        for (int i2 = 0; i2 < 4; ++i2) { t += ls[i2 * 2]; t2 += ls[i2 * 2 + 1]; }
        part[blockIdx.x * 2] = t; part[blockIdx.x * 2 + 1] = t2;
    }
}

// ---------------- GN apply (stats finalize folded in) -> hn FRAG-MAJOR bf16 ----------------
__global__ __launch_bounds__(256) void gn_apply(const float* x, const float* part,
                                                const float* gsc, const float* gbi,
                                                unsigned short* hnf) {
    int blk = blockIdx.x;                 // 2*3*48 = 288
    int b = blk / 144; int f = (blk % 144) / 48; int y = blk % 48;
    int c = threadIdx.x;
    int gid = b * 4 + (c >> 6);
    float s = 0.f, s2 = 0.f;              // finalize stats from 108 slice partials
    for (int i = 0; i < 108; ++i) {
        s  += part[(gid * 108 + i) * 2];
        s2 += part[(gid * 108 + i) * 2 + 1];
    }
    float mean = s / 442368.f;
    float rsig = rsqrtf(s2 / 442368.f - mean * mean + EPSG);
    float sc = gsc[c] * rsig, bi = gbi[c] - mean * sc;
    __shared__ unsigned short lds[48 * 256];
    const float* xr = x + (size_t)((f * 2 + b) * C + c) * HW + y * 48;
    #pragma unroll
    for (int xw = 0; xw < 48; xw += 4) {
        float4 v = *(const float4*)(xr + xw);
        lds[(xw + 0) * 256 + c] = f2bf(v.x * sc + bi);
        lds[(xw + 1) * 256 + c] = f2bf(v.y * sc + bi);
        lds[(xw + 2) * 256 + c] = f2bf(v.z * sc + bi);
        lds[(xw + 3) * 256 + c] = f2bf(v.w * sc + bi);
    }
    __syncthreads();
    int kc = c >> 5, gg = (c >> 3) & 3, j = c & 7;
    int nbase = f * HW + y * 48;
    for (int xw = 0; xw < 48; ++xw) {
        int n = nbase + xw;
        size_t idx = ((size_t)(((b * 108 + (n >> 6)) * 4 + ((n >> 4) & 3)) * 8 + kc)) * 512
                   + (gg * 16 + (n & 15)) * 8 + j;
        hnf[idx] = lds[xw * 256 + c];
    }
}

// ---------------- fused Q/K/V GEMM -> scaled-MFMA fp8 frag layouts ----------------
__global__ __launch_bounds__(256) void qkv_gemm(const unsigned short* hnf, const unsigned short* wbf,
                                                const float* bq, const float* bk, const float* bvp,
                                                u8* qfp, u8* kfp, u8* vfp) {
    __shared__ u8 tr[4096];
    int t = blockIdx.x;
    int tid = (int)threadIdx.x;
    int lane = tid & 63, w = tid >> 6;
    int l16 = lane & 15, g = lane >> 4;
    f32x4 acc[4] = {{0.f,0.f,0.f,0.f},{0.f,0.f,0.f,0.f},{0.f,0.f,0.f,0.f},{0.f,0.f,0.f,0.f}};
    if (t < 1728) {
        int sel = t / 864; int rem = t % 864;
        int b = rem / 432;  int rem2 = rem % 432;
        int pt = rem2 >> 2; int ot = rem2 & 3;
        const unsigned short* wsel = wbf + sel * 65536;
        const float* bias = sel ? bk : bq;
        u8* out = sel ? kfp : qfp;
        const unsigned short* af  = hnf + (size_t)(((b * 108 + pt) * 4 + w) * 8) * 512 + lane * 8;
        const unsigned short* bfm = wsel + (size_t)(ot * 4 * 8) * 512 + lane * 8;
        #pragma unroll
        for (int kk = 0; kk < 8; ++kk) {
            bf16x8 a = *(const bf16x8*)(af + kk * 512);
            #pragma unroll
            for (int f = 0; f < 4; ++f) {
                bf16x8 bb = *(const bf16x8*)(bfm + (f * 8 + kk) * 512);
                acc[f] = MFMA(a, bb, acc[f]);
            }
        }
        // scatter to LDS (n = pt*64 + w*16 + 4g+r, c = ot*64 + f*16 + l16)
        #pragma unroll
        for (int f = 0; f < 4; ++f) {
            float bv = bias[ot * 64 + f * 16 + l16];
            #pragma unroll
            for (int r = 0; r < 4; ++r)
                tr[w * 1024 + (f & 1) * 512 + ((f >> 1) * 16 + 4 * g + r) * 16 + l16]
                    = f2fp8(acc[f][r] + bv);
        }
        __syncthreads();
        int t2 = tid >> 6, hf = (tid >> 5) & 1, ln = tid & 31;
        size_t frag = ((size_t)(b * 108 + pt) * 4 + t2) * 2 + (ot >> 1);
        *(int4*)(out + frag * 2048 + hf * 1024 + ((ot & 1) * 32 + ln) * 16)
            = *(const int4*)(tr + tid * 16);
    } else {
        int tv = t - 1728;                        // 864 = 2 b * 4 ot * 108 pt
        int b = tv / 432; int rem2 = tv % 432;
        int ot = rem2 / 108; int pt = rem2 % 108;
        const unsigned short* wvw = wbf + 131072;
        const unsigned short* afm = wvw + (size_t)((ot * 4 + w) * 8) * 512 + lane * 8;
        const unsigned short* bfm = hnf + (size_t)((b * 108 + pt) * 4 * 8) * 512 + lane * 8;
        #pragma unroll
        for (int kk = 0; kk < 8; ++kk) {
            bf16x8 a = *(const bf16x8*)(afm + kk * 512);
            #pragma unroll
            for (int f = 0; f < 4; ++f) {
                bf16x8 bb = *(const bf16x8*)(bfm + (f * 8 + kk) * 512);
                acc[f] = MFMA(a, bb, acc[f]);
            }
        }
        // V (c-row = ot*64 + w*16 + 4g+r, n = pt*64 + f*16 + l16)
        #pragma unroll
        for (int f = 0; f < 4; ++f) {
            #pragma unroll
            for (int r = 0; r < 4; ++r) {
                int o = ot * 64 + w * 16 + 4 * g + r;
                tr[(w >> 1) * 2048 + (f & 1) * 1024
                   + ((f >> 1) * 32 + (w & 1) * 16 + 4 * g + r) * 16 + l16]
                    = f2fp8(acc[f][r] + bvp[o]);
            }
        }
        __syncthreads();
        size_t frag = (size_t)(b * 108 + pt) * 8 + ot * 2 + (tid >> 7);
        *(int4*)(vfp + frag * 2048 + (tid & 127) * 16) = *(const int4*)(tr + tid * 16);
    }
}

// ---------------- flash attention: MX-scaled fp8, triple-buffer, SINGLE score set --------
// 216 blocks x 512 threads, 8 waves x 32 q-rows. body(t) = { barrier; stage(t+2)->bs;
// softmax(S(t))->P; QK(t+1): S=0, accumulate from bn (WAR on S clears as softmax reads);
// PV(t) from bc }. Triple buffer => the barrier drains loads issued a FULL body earlier
// (staging latency off the critical path); QK's MFMAs sit between P ds_write and PV's
// P ds_read (lgkmcnt hidden). Register peak == R12 (single S set) -- no spill (R13 lesson:
// FETCH_SIZE is the spill canary).
__global__ __launch_bounds__(512, 2) void flash(const u8* qf, const u8* kf, const u8* vf,
                                                u8* po, float* lsg) {
    __shared__ char smem[114688];                 // 3 x 32KB K/V buffers + 8 x 2KB P
    int blk = blockIdx.x;                         // 216 = 8 XCD slots x 27 q-tiles(256)
    int x = blk & 7, qt = blk >> 3;
    int b = x >> 2, ks = x & 3;                   // XCD-pinned (b, KV-quarter)
    int slot = ks * 2 + b;
    int tid = (int)threadIdx.x;
    int lane = tid & 63, w = tid >> 6;            // w = wave 0..7
    int l16 = lane & 15, g = lane >> 4;
    int i0 = qt * 256 + w * 32;                   // wave covers 32 q-rows

    // Q B-frags (16x16x128): per (group u, c-half h) 32B/lane
    v8i qa[2][2];
    #pragma unroll
    for (int u = 0; u < 2; ++u)
        #pragma unroll
        for (int h = 0; h < 2; ++h) {
            const u8* qb = qf + ((((size_t)b * 108 + qt * 4 + (w >> 1)) * 4
                                  + ((2 * w + u) & 3)) * 2 + h) * 2048 + lane * 16;
            qa[u][h] = mk8(*(const int4*)qb, *(const int4*)(qb + 1024));
        }

    // staging: flat linear copy of 16KB frag-major tiles (advance 16KB/iter)
    size_t tb = (size_t)(b * 108 + ks * 27) * 16384;
    const u8* kst[2]; const u8* vst[2];
    #pragma unroll
    for (int q = 0; q < 2; ++q) {
        kst[q] = kf + tb + (q * 8 + w) * 1024 + lane * 16;
        vst[q] = vf + tb + (q * 8 + w) * 1024 + lane * 16;
    }
    // prologue: stage tiles 0 and 1 into bufs 0,1
    #pragma unroll
    for (int q = 0; q < 2; ++q) {
        gld16(kst[q], smem + (q * 8 + w) * 1024);
        gld16(vst[q], smem + 16384 + (q * 8 + w) * 1024);
        kst[q] += 16384; vst[q] += 16384;
    }
    #pragma unroll
    for (int q = 0; q < 2; ++q) {
        gld16(kst[q], smem + 32768 + (q * 8 + w) * 1024);
        gld16(vst[q], smem + 32768 + 16384 + (q * 8 + w) * 1024);
        kst[q] += 16384; vst[q] += 16384;
    }

    f32x16 oacc[8];
    #pragma unroll
    for (int ct = 0; ct < 8; ++ct)
        #pragma unroll
        for (int r = 0; r < 16; ++r) oacc[ct][r] = 0.f;
    float lsum0 = 0.f, lsum1 = 0.f;
    int pbase = 98304 + w * 2048;                 // per-wave P region
    f32x4 s4[2][4];                               // SINGLE score set (R13 spill lesson)
    int bc = 0, bn = 32768, bs = 65536;           // buffer offsets, rotate per body

    __syncthreads();                              // tiles 0,1 resident (drains prologue)

    // prologue QK(0) from buf 0 -> s4
    #pragma unroll
    for (int u = 0; u < 2; ++u)
        #pragma unroll
        for (int tt = 0; tt < 4; ++tt) s4[u][tt] = (f32x4){0.f,0.f,0.f,0.f};
    __builtin_amdgcn_s_setprio(1);
    #pragma unroll
    for (int tt = 0; tt < 4; ++tt)
        #pragma unroll
        for (int h = 0; h < 2; ++h) {
            const char* ka = smem + (tt * 2 + h) * 2048 + lane * 16;
            v8i a = mk8(*(const int4*)ka, *(const int4*)(ka + 1024));
            s4[0][tt] = MFMAS16(a, qa[0][h], s4[0][tt]);
            s4[1][tt] = MFMAS16(a, qa[1][h], s4[1][tt]);
        }
    __builtin_amdgcn_s_setprio(0);

    for (int t = 0; t < 27; ++t) {
        __syncthreads();                          // drains stage issued LAST body; protects bs
        if (t + 2 < 27) {                         // stage(t+2) -> bs (drained at next barrier)
            #pragma unroll
            for (int q = 0; q < 2; ++q) {
                gld16(kst[q], smem + bs + (q * 8 + w) * 1024);
                gld16(vst[q], smem + bs + 16384 + (q * 8 + w) * 1024);
                kst[q] += 16384; vst[q] += 16384;
            }
        }

        // softmax(S(t)) -> P (per-wave LDS, 32x32x64 A-frag layout) + lsum
        #pragma unroll
        for (int u = 0; u < 2; ++u) {
            float rs = 0.f;
            #pragma unroll
            for (int tt = 0; tt < 4; ++tt) {
                float p0 = __builtin_amdgcn_exp2f(fminf(s4[u][tt][0] * K2, 8.f));
                float p1 = __builtin_amdgcn_exp2f(fminf(s4[u][tt][1] * K2, 8.f));
                float p2 = __builtin_amdgcn_exp2f(fminf(s4[u][tt][2] * K2, 8.f));
                float p3 = __builtin_amdgcn_exp2f(fminf(s4[u][tt][3] * K2, 8.f));
                rs += (p0 + p1) + (p2 + p3);
                int lo = __builtin_amdgcn_cvt_pk_fp8_f32(p0, p1, 0, false);
                int d  = __builtin_amdgcn_cvt_pk_fp8_f32(p2, p3, lo, true);
                *(int*)(smem + pbase + u * 1024 + (tt >> 1) * 512 + l16 * 32
                        + (tt & 1) * 16 + g * 4) = d;
            }
            rs += __shfl_xor(rs, 16);
            rs += __shfl_xor(rs, 32);
            if (u == 0) lsum0 += rs; else lsum1 += rs;
        }

        // QK(t+1) from bn -> s4 (reuses S regs after softmax consumed them; staged a full
        // body ago so ds_reads never wait on fresh vmem). MFMAs also hide P's lgkmcnt.
        if (t + 1 < 27) {
            #pragma unroll
            for (int u = 0; u < 2; ++u)
                #pragma unroll
                for (int tt = 0; tt < 4; ++tt) s4[u][tt] = (f32x4){0.f,0.f,0.f,0.f};
            __builtin_amdgcn_s_setprio(1);
            #pragma unroll
            for (int tt = 0; tt < 4; ++tt)
                #pragma unroll
                for (int h = 0; h < 2; ++h) {
                    const char* ka = smem + bn + (tt * 2 + h) * 2048 + lane * 16;
                    v8i a = mk8(*(const int4*)ka, *(const int4*)(ka + 1024));
                    s4[0][tt] = MFMAS16(a, qa[0][h], s4[0][tt]);
                    s4[1][tt] = MFMAS16(a, qa[1][h], s4[1][tt]);
                }
            __builtin_amdgcn_s_setprio(0);
        }

        // PV(t): A = P (row = l&31, k = (l>>5)*32+j), B = V frags from bc
        {
            const char* pp = smem + pbase + ((lane >> 4) & 1) * 1024 + (lane >> 5) * 512
                           + l16 * 32;
            v8i pa = mk8(*(const int4*)pp, *(const int4*)(pp + 16));
            __builtin_amdgcn_s_setprio(1);
            #pragma unroll
            for (int ct = 0; ct < 8; ++ct) {
                const char* va = smem + bc + 16384 + ct * 2048 + lane * 16;
                v8i vv = mk8(*(const int4*)va, *(const int4*)(va + 1024));
                oacc[ct] = MFMAS32(pa, vv, oacc[ct]);
            }
            __builtin_amdgcn_s_setprio(0);
        }
        int tmp = bc; bc = bn; bn = bs; bs = tmp; // rotate buffers
    }

    // epilogue: unnormalized partials (fp8, 32x32 D layout) + lsum (f32)
    #pragma unroll
    for (int ct = 0; ct < 8; ++ct)
        #pragma unroll
        for (int r = 0; r < 16; ++r) {
            int n = i0 + (r & 3) + 8 * (r >> 2) + 4 * (lane >> 5);
            po[((size_t)slot * NPOS + n) * C + ct * 32 + (lane & 31)] = f2fp8(oacc[ct][r]);
        }
    if (lane < 16) {
        lsg[(size_t)slot * NPOS + i0 + lane]      = lsum0;
        lsg[(size_t)slot * NPOS + i0 + 16 + lane] = lsum1;
    }
}

// ---------------- proj (+ inline 4-way split combine) + bias + residual ----------------
__global__ __launch_bounds__(256) void proj(const u8* po, const float* lsg,
                                            const unsigned short* wbf,
                                            const float* bp, const float* x, float* out) {
    int t = blockIdx.x;                  // 2 b * 108 pt * 4 ot = 864
    int b = t / 432; int rem2 = t % 432;
    int pt = rem2 >> 2; int ot = rem2 & 3;
    int lane = threadIdx.x & 63, w = threadIdx.x >> 6;
    int l16 = lane & 15, g = lane >> 4;
    int n = pt * 64 + w * 16 + l16;      // this lane's A row
    float l = 0.f;
    #pragma unroll
    for (int ks2 = 0; ks2 < 4; ++ks2) l += lsg[(size_t)(ks2 * 2 + b) * NPOS + n];
    float rl = 1.f / l;
    const unsigned short* wpw = wbf + 196608;
    const unsigned short* bfm = wpw + (size_t)(ot * 4 * 8) * 512 + lane * 8;
    const u8* prow = po + ((size_t)b * NPOS + n) * C + g * 8;   // + ks2*2*NPOS*C + kk*32
    f32x4 acc[4] = {{0.f,0.f,0.f,0.f},{0.f,0.f,0.f,0.f},{0.f,0.f,0.f,0.f},{0.f,0.f,0.f,0.f}};
    #pragma unroll
    for (int kk = 0; kk < 8; ++kk) {
        float av0 = 0.f, av1 = 0.f, av2 = 0.f, av3 = 0.f;
        float av4 = 0.f, av5 = 0.f, av6 = 0.f, av7 = 0.f;
        #pragma unroll
        for (int ks2 = 0; ks2 < 4; ++ks2) {
            i64 p8 = *(const i64*)(prow + (size_t)ks2 * (2 * NPOS * 256) + kk * 32);
            av0 += fp8tof((u8)(p8));        av1 += fp8tof((u8)(p8 >> 8));
            av2 += fp8tof((u8)(p8 >> 16));  av3 += fp8tof((u8)(p8 >> 24));
            av4 += fp8tof((u8)(p8 >> 32));  av5 += fp8tof((u8)(p8 >> 40));
            av6 += fp8tof((u8)(p8 >> 48));  av7 += fp8tof((u8)(p8 >> 56));
        }
        bf16x8 a;
        a[0] = (short)f2bf(av0 * rl); a[1] = (short)f2bf(av1 * rl);
        a[2] = (short)f2bf(av2 * rl); a[3] = (short)f2bf(av3 * rl);
        a[4] = (short)f2bf(av4 * rl); a[5] = (short)f2bf(av5 * rl);
        a[6] = (short)f2bf(av6 * rl); a[7] = (short)f2bf(av7 * rl);
        #pragma unroll
        for (int f = 0; f < 4; ++f) {
            bf16x8 bb = *(const bf16x8*)(bfm + (f * 8 + kk) * 512);
            acc[f] = MFMA(a, bb, acc[f]);
        }
    }
    __shared__ float lt[64][72];
    #pragma unroll
    for (int f = 0; f < 4; ++f) {
        float bv = bp[ot * 64 + f * 16 + l16];
        #pragma unroll
        for (int r = 0; r < 4; ++r)
            lt[f * 16 + l16][w * 16 + 4 * g + r] = acc[f][r] + bv;
    }
    __syncthreads();
    int p0 = pt * 64;
    int f3 = p0 / HW; int sp0 = p0 - f3 * HW;     // 64 | 2304 so whole tile same f
    for (int it = 0; it < 16; ++it) {
        int ol = it * 4 + w;
        int pl = lane;
        size_t idx = ((size_t)(b * 3 + f3) * C + ot * 64 + ol) * HW + sp0 + pl;
        out[idx] = x[idx] + lt[ol][pl];
    }
}

extern "C" void kernel_launch(void* const* d_in, const int* in_sizes, int n_in,
                              void* d_out, int out_size, void* d_ws, size_t ws_size,
                              hipStream_t stream) {
    const float* x   = (const float*)d_in[0];
    const float* gsc = (const float*)d_in[1];
    const float* gbi = (const float*)d_in[2];
    const float* wq  = (const float*)d_in[3];
    const float* bq  = (const float*)d_in[4];
    const float* wk  = (const float*)d_in[5];
    const float* bk  = (const float*)d_in[6];
    const float* wv  = (const float*)d_in[7];
    const float* bv  = (const float*)d_in[8];
    const float* wp  = (const float*)d_in[9];
    const float* bp  = (const float*)d_in[10];

    char* ws = (char*)d_ws;
    unsigned short* wbf = (unsigned short*)(ws);             // 524288 B
    float* part         = (float*)(ws + 524288);             // 6912 B (8 groups x 108 x 2)
    unsigned short* hn  = (unsigned short*)(ws + 532480);    // 7077888 B (frag-major)
    u8* qfp             = (u8*)(ws + 7610368);               // 3538944 B
    u8* kfp             = (u8*)(ws + 11149312);              // 3538944 B
    u8* vfp             = (u8*)(ws + 14688256);              // 3538944 B
    u8* po              = (u8*)(ws + 18227200);              // 14155776 B (4ks x 2b x n x c)
    float* lsg          = (float*)(ws + 32382976);           // 221184 B -> end 32604160
    float* out = (float*)d_out;

    hipLaunchKernelGGL(gn_stats, dim3(864),  dim3(256), 0, stream, x, part, wq, wk, wv, wp, wbf);
    hipLaunchKernelGGL(gn_apply, dim3(288),  dim3(256), 0, stream, x, part, gsc, gbi, hn);
    hipLaunchKernelGGL(qkv_gemm, dim3(2592), dim3(256), 0, stream, hn, wbf, bq, bk, bv, qfp, kfp, vfp);
    hipLaunchKernelGGL(flash,    dim3(216),  dim3(512), 0, stream, qfp, kfp, vfp, po, lsg);
    hipLaunchKernelGGL(proj,     dim3(864),  dim3(256), 0, stream, po, lsg, wbf, bp, x, out);
}